// Round 15
// baseline (192.060 us; speedup 1.0000x reference)
//
#include <hip/hip_runtime.h>
#include <stdint.h>

#define N_NODES 100000
#define FEAT 64
#define SCAN_B 1024
#define BKT 256                                  // dst nodes per bucket
#define NBINS ((N_NODES + BKT - 1) / BKT)        // 391
#define NTILES 1024                              // edge tiles (4 wg/CU)
#define NRANGE 4                                 // src ranges (25000 nodes = 3.2MB, fits XCD L2)
#define RANGE_DIV 25000
#define SRC_MASK 0x00FFFFFFu

typedef __attribute__((ext_vector_type(8))) short bf16x8;
typedef __attribute__((ext_vector_type(4))) float f32x4;

__device__ __forceinline__ unsigned short f2bf(float f) {
    unsigned int u = __float_as_uint(f);
    u += 0x7fffu + ((u >> 16) & 1u);  // RNE
    return (unsigned short)(u >> 16);
}
__device__ __forceinline__ float bflo(unsigned int u) { return __uint_as_float(u << 16); }
__device__ __forceinline__ float bfhi(unsigned int u) { return __uint_as_float(u & 0xffff0000u); }

// ---- one-time fp32 -> bf16 feature conversion ----
__global__ __launch_bounds__(256) void cvt_bf16_kernel(
    const float* __restrict__ in, unsigned short* __restrict__ out, int n8) {
    int i = blockIdx.x * blockDim.x + threadIdx.x;
    if (i >= n8) return;
    float4 a = ((const float4*)in)[i * 2];
    float4 b = ((const float4*)in)[i * 2 + 1];
    uint4 r;
    r.x = (unsigned int)f2bf(a.x) | ((unsigned int)f2bf(a.y) << 16);
    r.y = (unsigned int)f2bf(a.z) | ((unsigned int)f2bf(a.w) << 16);
    r.z = (unsigned int)f2bf(b.x) | ((unsigned int)f2bf(b.y) << 16);
    r.w = (unsigned int)f2bf(b.z) | ((unsigned int)f2bf(b.w) << 16);
    ((uint4*)out)[i] = r;
}

// ---- bucket partition build ----

__global__ __launch_bounds__(256) void tile_hist_kernel(
    const int* __restrict__ dst, int* __restrict__ H, int nE, int tileEdges) {
    __shared__ int hist[NBINS];
    const int tile = blockIdx.x;
    const int tid = threadIdx.x;
    for (int i = tid; i < NBINS; i += 256) hist[i] = 0;
    __syncthreads();
    int e0 = tile * tileEdges;
    int e1 = min(e0 + tileEdges, nE);
    for (int e = e0 + tid; e < e1; e += 256) atomicAdd(&hist[dst[e] >> 8], 1);
    __syncthreads();
    for (int i = tid; i < NBINS; i += 256) H[i * NTILES + tile] = hist[i];
}

__global__ __launch_bounds__(SCAN_B) void scan1_kernel(
    const int* __restrict__ deg, int* __restrict__ P,
    int* __restrict__ bsum, int n) {
    __shared__ int tmp[SCAN_B];
    int t = threadIdx.x;
    int gid = blockIdx.x * SCAN_B + t;
    int v = (gid < n) ? deg[gid] : 0;
    tmp[t] = v;
    __syncthreads();
    for (int off = 1; off < SCAN_B; off <<= 1) {
        int a = (t >= off) ? tmp[t - off] : 0;
        __syncthreads();
        tmp[t] += a;
        __syncthreads();
    }
    if (gid < n) P[gid] = tmp[t] - v;  // exclusive
    if (t == SCAN_B - 1) bsum[blockIdx.x] = tmp[t];
}

__global__ __launch_bounds__(512) void scan2_kernel(int* __restrict__ bsum, int nb) {
    __shared__ int tmp[512];
    int t = threadIdx.x;
    int v = (t < nb) ? bsum[t] : 0;
    tmp[t] = v;
    __syncthreads();
    for (int off = 1; off < 512; off <<= 1) {
        int a = (t >= off) ? tmp[t - off] : 0;
        __syncthreads();
        tmp[t] += a;
        __syncthreads();
    }
    if (t < nb) bsum[t] = tmp[t] - v;  // exclusive
}

__global__ __launch_bounds__(256) void scan3_kernel(
    int* __restrict__ P, const int* __restrict__ bsum, int n, int total) {
    int gid = blockIdx.x * blockDim.x + threadIdx.x;
    if (gid < n) P[gid] += bsum[gid >> 10];
    if (gid == 0) P[n] = total;
}

__global__ __launch_bounds__(256) void scatter_bucket_kernel(
    const int* __restrict__ src, const int* __restrict__ dst,
    const int* __restrict__ P, unsigned int* __restrict__ packed,
    int nE, int tileEdges) {
    __shared__ int cur[NBINS];
    const int tile = blockIdx.x;
    const int tid = threadIdx.x;
    for (int i = tid; i < NBINS; i += 256) cur[i] = P[i * NTILES + tile];
    __syncthreads();
    int e0 = tile * tileEdges;
    int e1 = min(e0 + tileEdges, nE);
    for (int e = e0 + tid; e < e1; e += 256) {
        int d = dst[e];
        int pos = atomicAdd(&cur[d >> 8], 1);
        packed[pos] = ((unsigned int)(d & (BKT - 1)) << 24) | (unsigned int)src[e];
    }
}

// 1024-bin counting sort per bucket: key = dloc*4 + src/25000.
__global__ __launch_bounds__(256) void bucket_sort_kernel(
    const unsigned int* __restrict__ packed,
    const int* __restrict__ P,
    int* __restrict__ rowptr2,
    float* __restrict__ invdeg,
    int* __restrict__ ssrc,
    int nE) {
    __shared__ int hist[BKT * NRANGE];
    __shared__ int cur[BKT * NRANGE];
    __shared__ int scanbuf[BKT];
    const int b = blockIdx.x;
    const int t = threadIdx.x;

#pragma unroll
    for (int i = 0; i < NRANGE; ++i) hist[t * NRANGE + i] = 0;
    __syncthreads();
    const int start = P[b * NTILES];
    const int end = (b + 1 < NBINS) ? P[(b + 1) * NTILES] : nE;
    for (int j = start + t; j < end; j += 256) {
        unsigned int p = packed[j];
        int s = (int)(p & SRC_MASK);
        atomicAdd(&hist[(int)(p >> 24) * NRANGE + s / RANGE_DIV], 1);
    }
    __syncthreads();

    int c0 = hist[t * NRANGE + 0], c1 = hist[t * NRANGE + 1];
    int c2 = hist[t * NRANGE + 2], c3 = hist[t * NRANGE + 3];
    int tot = c0 + c1 + c2 + c3;
    int node = b * BKT + t;
    if (node < N_NODES) invdeg[node] = 1.0f / (float)(tot > 0 ? tot : 1);
    scanbuf[t] = tot;
    __syncthreads();
    for (int off = 1; off < 256; off <<= 1) {
        int a = (t >= off) ? scanbuf[t - off] : 0;
        __syncthreads();
        scanbuf[t] += a;
        __syncthreads();
    }
    int base = start + scanbuf[t] - tot;  // exclusive within bucket
    int e0 = base, e1 = base + c0, e2 = e1 + c1, e3 = e2 + c2;
    rowptr2[node * 4 + 0] = e0;
    rowptr2[node * 4 + 1] = e1;
    rowptr2[node * 4 + 2] = e2;
    rowptr2[node * 4 + 3] = e3;
    cur[t * NRANGE + 0] = e0;
    cur[t * NRANGE + 1] = e1;
    cur[t * NRANGE + 2] = e2;
    cur[t * NRANGE + 3] = e3;
    __syncthreads();

    for (int j = start + t; j < end; j += 256) {
        unsigned int p = packed[j];
        int s = (int)(p & SRC_MASK);
        int pos = atomicAdd(&cur[(int)(p >> 24) * NRANGE + s / RANGE_DIV], 1);
        ssrc[pos] = s;
    }
}

// Range-partitioned partial aggregation (L2-resident gathers, R14-proven).
__global__ __launch_bounds__(256) void agg_part_kernel(
    const unsigned short* __restrict__ featb,   // [N][64] bf16
    const int* __restrict__ rowptr2,            // [N*4+4]
    const int* __restrict__ ssrc,
    unsigned short* __restrict__ part,          // [4][N][64] bf16
    int nNodes) {
    const int c = blockIdx.x & 3;
    const int bin = blockIdx.x >> 2;
    const int slot = threadIdx.x >> 3;  // 0..31
    const int chunk = threadIdx.x & 7;
    const uint4* feat16 = (const uint4*)featb;

#pragma unroll
    for (int g = 0; g < 8; ++g) {
        int node = bin * BKT + g * 32 + slot;
        if (node >= nNodes) continue;
        int beg = rowptr2[node * 4 + c];
        int end = rowptr2[node * 4 + c + 1];
        float acc0 = 0.f, acc1 = 0.f, acc2 = 0.f, acc3 = 0.f;
        float acc4 = 0.f, acc5 = 0.f, acc6 = 0.f, acc7 = 0.f;

#define ADDROW(a)                                 \
    acc0 += bflo((a).x); acc1 += bfhi((a).x);     \
    acc2 += bflo((a).y); acc3 += bfhi((a).y);     \
    acc4 += bflo((a).z); acc5 += bfhi((a).z);     \
    acc6 += bflo((a).w); acc7 += bfhi((a).w);

        int j = beg;
        for (; j + 4 <= end; j += 4) {
            int s0 = ssrc[j + 0];
            int s1 = ssrc[j + 1];
            int s2 = ssrc[j + 2];
            int s3 = ssrc[j + 3];
            uint4 a0 = feat16[(size_t)s0 * 8 + chunk];
            uint4 a1 = feat16[(size_t)s1 * 8 + chunk];
            uint4 a2 = feat16[(size_t)s2 * 8 + chunk];
            uint4 a3 = feat16[(size_t)s3 * 8 + chunk];
            ADDROW(a0) ADDROW(a1) ADDROW(a2) ADDROW(a3)
        }
        for (; j < end; ++j) {
            uint4 a = feat16[(size_t)ssrc[j] * 8 + chunk];
            ADDROW(a)
        }
#undef ADDROW

        uint4 r;
        r.x = (unsigned int)f2bf(acc0) | ((unsigned int)f2bf(acc1) << 16);
        r.y = (unsigned int)f2bf(acc2) | ((unsigned int)f2bf(acc3) << 16);
        r.z = (unsigned int)f2bf(acc4) | ((unsigned int)f2bf(acc5) << 16);
        r.w = (unsigned int)f2bf(acc6) | ((unsigned int)f2bf(acc7) << 16);
        ((uint4*)part)[((size_t)c * N_NODES + node) * 8 + chunk] = r;
    }
}

// ---- MFMA linear with fused partial-reduce ----

__device__ __forceinline__ bf16x8 pack8(const float* __restrict__ p) {
    float4 a = *(const float4*)p;
    float4 b = *(const float4*)(p + 4);
    bf16x8 r;
    r[0] = (short)f2bf(a.x); r[1] = (short)f2bf(a.y);
    r[2] = (short)f2bf(a.z); r[3] = (short)f2bf(a.w);
    r[4] = (short)f2bf(b.x); r[5] = (short)f2bf(b.y);
    r[6] = (short)f2bf(b.z); r[7] = (short)f2bf(b.w);
    return r;
}

template <bool OUT_BF16>
__global__ __launch_bounds__(256) void mfma_linear_kernel(
    const unsigned short* __restrict__ part,   // [4][N][64] bf16 partials
    const float* __restrict__ invdeg,          // [N]
    const unsigned short* __restrict__ xb,     // [N][64] bf16
    const float* __restrict__ Wl,
    const float* __restrict__ bias,
    const float* __restrict__ Wr,
    void* __restrict__ outp,
    int nGroups) {
    const int lane = (int)(threadIdx.x & 63);
    const int col = lane & 15;
    const int kg = lane >> 4;
    const uint4* part4 = (const uint4*)part;

    bf16x8 bfr[4][4];
#pragma unroll
    for (int t = 0; t < 4; ++t) {
        const int n = t * 16 + col;
#pragma unroll
        for (int kk = 0; kk < 4; ++kk) {
            const float* w = (kk < 2 ? Wl : Wr) + n * 64 + (kk & 1) * 32 + kg * 8;
            bfr[t][kk] = pack8(w);
        }
    }
    float bv[4];
#pragma unroll
    for (int t = 0; t < 4; ++t) bv[t] = bias[t * 16 + col];

    const int wave = (int)((blockIdx.x * blockDim.x + threadIdx.x) >> 6);
    const int nWaves = (int)((gridDim.x * blockDim.x) >> 6);

    for (int g = wave; g < nGroups; g += nWaves) {
        const int arow = g * 16 + col;
        const float invd = invdeg[arow];
        const unsigned short* xrow = xb + (size_t)arow * FEAT + kg * 8;

        f32x4 acc[4];
#pragma unroll
        for (int t = 0; t < 4; ++t) acc[t] = (f32x4){0.f, 0.f, 0.f, 0.f};

#pragma unroll
        for (int kk = 0; kk < 4; ++kk) {
            bf16x8 a;
            if (kk < 2) {
                const size_t u = (size_t)arow * 8 + (kk & 1) * 4 + kg;
                uint4 q0 = part4[u];
                uint4 q1 = part4[(size_t)1 * N_NODES * 8 + u];
                uint4 q2 = part4[(size_t)2 * N_NODES * 8 + u];
                uint4 q3 = part4[(size_t)3 * N_NODES * 8 + u];
                float m0 = (bflo(q0.x) + bflo(q1.x)) + (bflo(q2.x) + bflo(q3.x));
                float m1 = (bfhi(q0.x) + bfhi(q1.x)) + (bfhi(q2.x) + bfhi(q3.x));
                float m2 = (bflo(q0.y) + bflo(q1.y)) + (bflo(q2.y) + bflo(q3.y));
                float m3 = (bfhi(q0.y) + bfhi(q1.y)) + (bfhi(q2.y) + bfhi(q3.y));
                float m4 = (bflo(q0.z) + bflo(q1.z)) + (bflo(q2.z) + bflo(q3.z));
                float m5 = (bfhi(q0.z) + bfhi(q1.z)) + (bfhi(q2.z) + bfhi(q3.z));
                float m6 = (bflo(q0.w) + bflo(q1.w)) + (bflo(q2.w) + bflo(q3.w));
                float m7 = (bfhi(q0.w) + bfhi(q1.w)) + (bfhi(q2.w) + bfhi(q3.w));
                a[0] = (short)f2bf(m0 * invd); a[1] = (short)f2bf(m1 * invd);
                a[2] = (short)f2bf(m2 * invd); a[3] = (short)f2bf(m3 * invd);
                a[4] = (short)f2bf(m4 * invd); a[5] = (short)f2bf(m5 * invd);
                a[6] = (short)f2bf(m6 * invd); a[7] = (short)f2bf(m7 * invd);
            } else {
                a = *(const bf16x8*)(xrow + (kk & 1) * 32);
            }
#pragma unroll
            for (int t = 0; t < 4; ++t)
                acc[t] = __builtin_amdgcn_mfma_f32_16x16x32_bf16(a, bfr[t][kk], acc[t], 0, 0, 0);
        }

#pragma unroll
        for (int t = 0; t < 4; ++t) {
#pragma unroll
            for (int r = 0; r < 4; ++r) {
                int node = g * 16 + kg * 4 + r;
                float v = fmaxf(acc[t][r] + bv[t], 0.0f);
                if (OUT_BF16)
                    ((unsigned short*)outp)[(size_t)node * FEAT + t * 16 + col] = f2bf(v);
                else
                    ((float*)outp)[(size_t)node * FEAT + t * 16 + col] = v;
            }
        }
    }
}

extern "C" void kernel_launch(void* const* d_in, const int* in_sizes, int n_in,
                              void* d_out, int out_size, void* d_ws, size_t ws_size,
                              hipStream_t stream) {
    const float* x   = (const float*)d_in[0];
    const int* ei    = (const int*)d_in[1];
    const float* Wl1 = (const float*)d_in[2];
    const float* b1  = (const float*)d_in[3];
    const float* Wr1 = (const float*)d_in[4];
    const float* Wl2 = (const float*)d_in[5];
    const float* b2  = (const float*)d_in[6];
    const float* Wr2 = (const float*)d_in[7];

    const int E = in_sizes[1] / 2;  // 1,600,000
    const int* src = ei;
    const int* dst = ei + E;
    const int N = N_NODES;

    const int n2 = NBINS * NTILES;               // 400384
    const int TE = (E + NTILES - 1) / NTILES;    // 1563
    const int NB2 = (n2 + SCAN_B - 1) / SCAN_B;  // 391

    // workspace layout
    int* H        = (int*)d_ws;                          // n2
    int* P        = H + n2;                              // n2+8
    int* bsum     = P + (n2 + 8);                        // 512
    int* rowptr2  = bsum + 512;                          // n2 (covers N*4+tail)
    float* invdeg = (float*)(rowptr2 + n2);              // N
    int* ssrc     = (int*)(invdeg + N);                  // E
    unsigned short* xb = (unsigned short*)(ssrc + E);    // N*64 bf16
    unsigned short* hb = xb + (size_t)N * FEAT;          // N*64 bf16
    unsigned short* part = hb + (size_t)N * FEAT;        // 4*N*64 bf16 (51.2MB)
    unsigned int* packed = (unsigned int*)part;          // E (dead before part is written)
    float* out = (float*)d_out;

    const int NG = N / 16;  // 6250 MFMA node-groups

    // ---- feature conversion + partition/sort (reused by both layers) ----
    cvt_bf16_kernel<<<(N * FEAT / 8 + 255) / 256, 256, 0, stream>>>(x, xb, N * FEAT / 8);
    tile_hist_kernel<<<NTILES, 256, 0, stream>>>(dst, H, E, TE);
    scan1_kernel<<<NB2, SCAN_B, 0, stream>>>(H, P, bsum, n2);
    scan2_kernel<<<1, 512, 0, stream>>>(bsum, NB2);
    scan3_kernel<<<(n2 + 256) / 256, 256, 0, stream>>>(P, bsum, n2, E);
    scatter_bucket_kernel<<<NTILES, 256, 0, stream>>>(src, dst, P, packed, E, TE);
    bucket_sort_kernel<<<NBINS, 256, 0, stream>>>(packed, P, rowptr2, invdeg, ssrc, E);

    // ---- layer 1 ----
    agg_part_kernel<<<NBINS * NRANGE, 256, 0, stream>>>(xb, rowptr2, ssrc, part, N);
    mfma_linear_kernel<true><<<1024, 256, 0, stream>>>(part, invdeg, xb, Wl1, b1, Wr1, hb, NG);

    // ---- layer 2 ----
    agg_part_kernel<<<NBINS * NRANGE, 256, 0, stream>>>(hb, rowptr2, ssrc, part, N);
    mfma_linear_kernel<false><<<1024, 256, 0, stream>>>(part, invdeg, hb, Wl2, b2, Wr2, out, NG);
}

// Round 16
// 176.706 us; speedup vs baseline: 1.0869x; 1.0869x over previous
//
#include <hip/hip_runtime.h>
#include <stdint.h>

#define N_NODES 100000
#define FEAT 64
#define SCAN_B 1024
#define BKT 256                                  // dst nodes per bucket
#define NBINS ((N_NODES + BKT - 1) / BKT)        // 391
#define NTILES 1024                              // edge tiles (4 wg/CU)
#define NRANGE 4                                 // src ranges (25000 nodes = 3.2MB, fits XCD L2)
#define RANGE_DIV 25000
#define SRC_MASK 0x00FFFFFFu

typedef __attribute__((ext_vector_type(8))) short bf16x8;
typedef __attribute__((ext_vector_type(4))) float f32x4;

__device__ __forceinline__ unsigned short f2bf(float f) {
    unsigned int u = __float_as_uint(f);
    u += 0x7fffu + ((u >> 16) & 1u);  // RNE
    return (unsigned short)(u >> 16);
}
__device__ __forceinline__ float bflo(unsigned int u) { return __uint_as_float(u << 16); }
__device__ __forceinline__ float bfhi(unsigned int u) { return __uint_as_float(u & 0xffff0000u); }

// ---- one-time fp32 -> bf16 feature conversion ----
__global__ __launch_bounds__(256) void cvt_bf16_kernel(
    const float* __restrict__ in, unsigned short* __restrict__ out, int n8) {
    int i = blockIdx.x * blockDim.x + threadIdx.x;
    if (i >= n8) return;
    float4 a = ((const float4*)in)[i * 2];
    float4 b = ((const float4*)in)[i * 2 + 1];
    uint4 r;
    r.x = (unsigned int)f2bf(a.x) | ((unsigned int)f2bf(a.y) << 16);
    r.y = (unsigned int)f2bf(a.z) | ((unsigned int)f2bf(a.w) << 16);
    r.z = (unsigned int)f2bf(b.x) | ((unsigned int)f2bf(b.y) << 16);
    r.w = (unsigned int)f2bf(b.z) | ((unsigned int)f2bf(b.w) << 16);
    ((uint4*)out)[i] = r;
}

// ---- bucket partition build ----

__global__ __launch_bounds__(256) void tile_hist_kernel(
    const int* __restrict__ dst, int* __restrict__ H, int nE, int tileEdges) {
    __shared__ int hist[NBINS];
    const int tile = blockIdx.x;
    const int tid = threadIdx.x;
    for (int i = tid; i < NBINS; i += 256) hist[i] = 0;
    __syncthreads();
    int e0 = tile * tileEdges;
    int e1 = min(e0 + tileEdges, nE);
    for (int e = e0 + tid; e < e1; e += 256) atomicAdd(&hist[dst[e] >> 8], 1);
    __syncthreads();
    for (int i = tid; i < NBINS; i += 256) H[i * NTILES + tile] = hist[i];
}

__global__ __launch_bounds__(SCAN_B) void scan1_kernel(
    const int* __restrict__ deg, int* __restrict__ P,
    int* __restrict__ bsum, int n) {
    __shared__ int tmp[SCAN_B];
    int t = threadIdx.x;
    int gid = blockIdx.x * SCAN_B + t;
    int v = (gid < n) ? deg[gid] : 0;
    tmp[t] = v;
    __syncthreads();
    for (int off = 1; off < SCAN_B; off <<= 1) {
        int a = (t >= off) ? tmp[t - off] : 0;
        __syncthreads();
        tmp[t] += a;
        __syncthreads();
    }
    if (gid < n) P[gid] = tmp[t] - v;  // exclusive
    if (t == SCAN_B - 1) bsum[blockIdx.x] = tmp[t];
}

// Fused scan2+scan3: each block recomputes the <=512-wide exclusive scan of
// bsum in LDS (391 broadcast loads, L2-hit), then applies the block offset.
__global__ __launch_bounds__(512) void scan23_kernel(
    int* __restrict__ P, const int* __restrict__ bsum, int n, int nb) {
    __shared__ int sb[512];
    int t = threadIdx.x;
    int v = (t < nb) ? bsum[t] : 0;
    sb[t] = v;
    __syncthreads();
    for (int off = 1; off < 512; off <<= 1) {
        int a = (t >= off) ? sb[t - off] : 0;
        __syncthreads();
        sb[t] += a;
        __syncthreads();
    }
    // sb = inclusive scan of bsum
    int gid = blockIdx.x * 512 + t;
    if (gid < n) {
        int blk = gid >> 10;  // scan1 block id (SCAN_B = 1024)
        P[gid] += sb[blk] - bsum[blk];  // exclusive offset
    }
    if (gid == 0) P[n] = sb[nb - 1];  // total
}

__global__ __launch_bounds__(256) void scatter_bucket_kernel(
    const int* __restrict__ src, const int* __restrict__ dst,
    const int* __restrict__ P, unsigned int* __restrict__ packed,
    int nE, int tileEdges) {
    __shared__ int cur[NBINS];
    const int tile = blockIdx.x;
    const int tid = threadIdx.x;
    for (int i = tid; i < NBINS; i += 256) cur[i] = P[i * NTILES + tile];
    __syncthreads();
    int e0 = tile * tileEdges;
    int e1 = min(e0 + tileEdges, nE);
    for (int e = e0 + tid; e < e1; e += 256) {
        int d = dst[e];
        int pos = atomicAdd(&cur[d >> 8], 1);
        packed[pos] = ((unsigned int)(d & (BKT - 1)) << 24) | (unsigned int)src[e];
    }
}

// 1024-bin counting sort per bucket: key = dloc*4 + src/25000.
__global__ __launch_bounds__(256) void bucket_sort_kernel(
    const unsigned int* __restrict__ packed,
    const int* __restrict__ P,
    int* __restrict__ rowptr2,
    float* __restrict__ invdeg,
    int* __restrict__ ssrc,
    int nE) {
    __shared__ int hist[BKT * NRANGE];
    __shared__ int cur[BKT * NRANGE];
    __shared__ int scanbuf[BKT];
    const int b = blockIdx.x;
    const int t = threadIdx.x;

#pragma unroll
    for (int i = 0; i < NRANGE; ++i) hist[t * NRANGE + i] = 0;
    __syncthreads();
    const int start = P[b * NTILES];
    const int end = (b + 1 < NBINS) ? P[(b + 1) * NTILES] : nE;
    for (int j = start + t; j < end; j += 256) {
        unsigned int p = packed[j];
        int s = (int)(p & SRC_MASK);
        atomicAdd(&hist[(int)(p >> 24) * NRANGE + s / RANGE_DIV], 1);
    }
    __syncthreads();

    int c0 = hist[t * NRANGE + 0], c1 = hist[t * NRANGE + 1];
    int c2 = hist[t * NRANGE + 2], c3 = hist[t * NRANGE + 3];
    int tot = c0 + c1 + c2 + c3;
    int node = b * BKT + t;
    if (node < N_NODES) invdeg[node] = 1.0f / (float)(tot > 0 ? tot : 1);
    scanbuf[t] = tot;
    __syncthreads();
    for (int off = 1; off < 256; off <<= 1) {
        int a = (t >= off) ? scanbuf[t - off] : 0;
        __syncthreads();
        scanbuf[t] += a;
        __syncthreads();
    }
    int base = start + scanbuf[t] - tot;  // exclusive within bucket
    int e0 = base, e1 = base + c0, e2 = e1 + c1, e3 = e2 + c2;
    rowptr2[node * 4 + 0] = e0;
    rowptr2[node * 4 + 1] = e1;
    rowptr2[node * 4 + 2] = e2;
    rowptr2[node * 4 + 3] = e3;
    cur[t * NRANGE + 0] = e0;
    cur[t * NRANGE + 1] = e1;
    cur[t * NRANGE + 2] = e2;
    cur[t * NRANGE + 3] = e3;
    __syncthreads();

    for (int j = start + t; j < end; j += 256) {
        unsigned int p = packed[j];
        int s = (int)(p & SRC_MASK);
        int pos = atomicAdd(&cur[(int)(p >> 24) * NRANGE + s / RANGE_DIV], 1);
        ssrc[pos] = s;
    }
}

// Range-partitioned partial aggregation (L2-resident gathers, R14-proven).
__global__ __launch_bounds__(256) void agg_part_kernel(
    const unsigned short* __restrict__ featb,   // [N][64] bf16
    const int* __restrict__ rowptr2,            // [N*4+4]
    const int* __restrict__ ssrc,
    unsigned short* __restrict__ part,          // [4][N][64] bf16
    int nNodes) {
    const int c = blockIdx.x & 3;
    const int bin = blockIdx.x >> 2;
    const int slot = threadIdx.x >> 3;  // 0..31
    const int chunk = threadIdx.x & 7;
    const uint4* feat16 = (const uint4*)featb;

#pragma unroll
    for (int g = 0; g < 8; ++g) {
        int node = bin * BKT + g * 32 + slot;
        if (node >= nNodes) continue;
        int beg = rowptr2[node * 4 + c];
        int end = rowptr2[node * 4 + c + 1];
        float acc0 = 0.f, acc1 = 0.f, acc2 = 0.f, acc3 = 0.f;
        float acc4 = 0.f, acc5 = 0.f, acc6 = 0.f, acc7 = 0.f;

#define ADDROW(a)                                 \
    acc0 += bflo((a).x); acc1 += bfhi((a).x);     \
    acc2 += bflo((a).y); acc3 += bfhi((a).y);     \
    acc4 += bflo((a).z); acc5 += bfhi((a).z);     \
    acc6 += bflo((a).w); acc7 += bfhi((a).w);

        int j = beg;
        for (; j + 4 <= end; j += 4) {
            int s0 = ssrc[j + 0];
            int s1 = ssrc[j + 1];
            int s2 = ssrc[j + 2];
            int s3 = ssrc[j + 3];
            uint4 a0 = feat16[(size_t)s0 * 8 + chunk];
            uint4 a1 = feat16[(size_t)s1 * 8 + chunk];
            uint4 a2 = feat16[(size_t)s2 * 8 + chunk];
            uint4 a3 = feat16[(size_t)s3 * 8 + chunk];
            ADDROW(a0) ADDROW(a1) ADDROW(a2) ADDROW(a3)
        }
        for (; j < end; ++j) {
            uint4 a = feat16[(size_t)ssrc[j] * 8 + chunk];
            ADDROW(a)
        }
#undef ADDROW

        uint4 r;
        r.x = (unsigned int)f2bf(acc0) | ((unsigned int)f2bf(acc1) << 16);
        r.y = (unsigned int)f2bf(acc2) | ((unsigned int)f2bf(acc3) << 16);
        r.z = (unsigned int)f2bf(acc4) | ((unsigned int)f2bf(acc5) << 16);
        r.w = (unsigned int)f2bf(acc6) | ((unsigned int)f2bf(acc7) << 16);
        ((uint4*)part)[((size_t)c * N_NODES + node) * 8 + chunk] = r;
    }
}

// ---- MFMA linear with fused partial-reduce ----

__device__ __forceinline__ bf16x8 pack8(const float* __restrict__ p) {
    float4 a = *(const float4*)p;
    float4 b = *(const float4*)(p + 4);
    bf16x8 r;
    r[0] = (short)f2bf(a.x); r[1] = (short)f2bf(a.y);
    r[2] = (short)f2bf(a.z); r[3] = (short)f2bf(a.w);
    r[4] = (short)f2bf(b.x); r[5] = (short)f2bf(b.y);
    r[6] = (short)f2bf(b.z); r[7] = (short)f2bf(b.w);
    return r;
}

template <bool OUT_BF16>
__global__ __launch_bounds__(256) void mfma_linear_kernel(
    const unsigned short* __restrict__ part,   // [4][N][64] bf16 partials
    const float* __restrict__ invdeg,          // [N]
    const unsigned short* __restrict__ xb,     // [N][64] bf16
    const float* __restrict__ Wl,
    const float* __restrict__ bias,
    const float* __restrict__ Wr,
    void* __restrict__ outp,
    int nGroups) {
    const int lane = (int)(threadIdx.x & 63);
    const int col = lane & 15;
    const int kg = lane >> 4;
    const uint4* part4 = (const uint4*)part;

    bf16x8 bfr[4][4];
#pragma unroll
    for (int t = 0; t < 4; ++t) {
        const int n = t * 16 + col;
#pragma unroll
        for (int kk = 0; kk < 4; ++kk) {
            const float* w = (kk < 2 ? Wl : Wr) + n * 64 + (kk & 1) * 32 + kg * 8;
            bfr[t][kk] = pack8(w);
        }
    }
    float bv[4];
#pragma unroll
    for (int t = 0; t < 4; ++t) bv[t] = bias[t * 16 + col];

    const int wave = (int)((blockIdx.x * blockDim.x + threadIdx.x) >> 6);
    const int nWaves = (int)((gridDim.x * blockDim.x) >> 6);

    for (int g = wave; g < nGroups; g += nWaves) {
        const int arow = g * 16 + col;
        const float invd = invdeg[arow];
        const unsigned short* xrow = xb + (size_t)arow * FEAT + kg * 8;

        f32x4 acc[4];
#pragma unroll
        for (int t = 0; t < 4; ++t) acc[t] = (f32x4){0.f, 0.f, 0.f, 0.f};

#pragma unroll
        for (int kk = 0; kk < 4; ++kk) {
            bf16x8 a;
            if (kk < 2) {
                const size_t u = (size_t)arow * 8 + (kk & 1) * 4 + kg;
                uint4 q0 = part4[u];
                uint4 q1 = part4[(size_t)1 * N_NODES * 8 + u];
                uint4 q2 = part4[(size_t)2 * N_NODES * 8 + u];
                uint4 q3 = part4[(size_t)3 * N_NODES * 8 + u];
                float m0 = (bflo(q0.x) + bflo(q1.x)) + (bflo(q2.x) + bflo(q3.x));
                float m1 = (bfhi(q0.x) + bfhi(q1.x)) + (bfhi(q2.x) + bfhi(q3.x));
                float m2 = (bflo(q0.y) + bflo(q1.y)) + (bflo(q2.y) + bflo(q3.y));
                float m3 = (bfhi(q0.y) + bfhi(q1.y)) + (bfhi(q2.y) + bfhi(q3.y));
                float m4 = (bflo(q0.z) + bflo(q1.z)) + (bflo(q2.z) + bflo(q3.z));
                float m5 = (bfhi(q0.z) + bfhi(q1.z)) + (bfhi(q2.z) + bfhi(q3.z));
                float m6 = (bflo(q0.w) + bflo(q1.w)) + (bflo(q2.w) + bflo(q3.w));
                float m7 = (bfhi(q0.w) + bfhi(q1.w)) + (bfhi(q2.w) + bfhi(q3.w));
                a[0] = (short)f2bf(m0 * invd); a[1] = (short)f2bf(m1 * invd);
                a[2] = (short)f2bf(m2 * invd); a[3] = (short)f2bf(m3 * invd);
                a[4] = (short)f2bf(m4 * invd); a[5] = (short)f2bf(m5 * invd);
                a[6] = (short)f2bf(m6 * invd); a[7] = (short)f2bf(m7 * invd);
            } else {
                a = *(const bf16x8*)(xrow + (kk & 1) * 32);
            }
#pragma unroll
            for (int t = 0; t < 4; ++t)
                acc[t] = __builtin_amdgcn_mfma_f32_16x16x32_bf16(a, bfr[t][kk], acc[t], 0, 0, 0);
        }

#pragma unroll
        for (int t = 0; t < 4; ++t) {
#pragma unroll
            for (int r = 0; r < 4; ++r) {
                int node = g * 16 + kg * 4 + r;
                float v = fmaxf(acc[t][r] + bv[t], 0.0f);
                if (OUT_BF16)
                    ((unsigned short*)outp)[(size_t)node * FEAT + t * 16 + col] = f2bf(v);
                else
                    ((float*)outp)[(size_t)node * FEAT + t * 16 + col] = v;
            }
        }
    }
}

extern "C" void kernel_launch(void* const* d_in, const int* in_sizes, int n_in,
                              void* d_out, int out_size, void* d_ws, size_t ws_size,
                              hipStream_t stream) {
    const float* x   = (const float*)d_in[0];
    const int* ei    = (const int*)d_in[1];
    const float* Wl1 = (const float*)d_in[2];
    const float* b1  = (const float*)d_in[3];
    const float* Wr1 = (const float*)d_in[4];
    const float* Wl2 = (const float*)d_in[5];
    const float* b2  = (const float*)d_in[6];
    const float* Wr2 = (const float*)d_in[7];

    const int E = in_sizes[1] / 2;  // 1,600,000
    const int* src = ei;
    const int* dst = ei + E;
    const int N = N_NODES;

    const int n2 = NBINS * NTILES;               // 400384
    const int TE = (E + NTILES - 1) / NTILES;    // 1563
    const int NB2 = (n2 + SCAN_B - 1) / SCAN_B;  // 391

    // workspace layout
    int* H        = (int*)d_ws;                          // n2
    int* P        = H + n2;                              // n2+8
    int* bsum     = P + (n2 + 8);                        // 512
    int* rowptr2  = bsum + 512;                          // n2 (covers N*4+tail)
    float* invdeg = (float*)(rowptr2 + n2);              // N
    int* ssrc     = (int*)(invdeg + N);                  // E
    unsigned short* xb = (unsigned short*)(ssrc + E);    // N*64 bf16
    unsigned short* hb = xb + (size_t)N * FEAT;          // N*64 bf16
    unsigned short* part = hb + (size_t)N * FEAT;        // 4*N*64 bf16 (51.2MB)
    unsigned int* packed = (unsigned int*)part;          // E (dead before part is written)
    float* out = (float*)d_out;

    const int NG = N / 16;  // 6250 MFMA node-groups

    // ---- feature conversion + partition/sort (reused by both layers) ----
    cvt_bf16_kernel<<<(N * FEAT / 8 + 255) / 256, 256, 0, stream>>>(x, xb, N * FEAT / 8);
    tile_hist_kernel<<<NTILES, 256, 0, stream>>>(dst, H, E, TE);
    scan1_kernel<<<NB2, SCAN_B, 0, stream>>>(H, P, bsum, n2);
    scan23_kernel<<<(n2 + 511) / 512, 512, 0, stream>>>(P, bsum, n2, NB2);
    scatter_bucket_kernel<<<NTILES, 256, 0, stream>>>(src, dst, P, packed, E, TE);
    bucket_sort_kernel<<<NBINS, 256, 0, stream>>>(packed, P, rowptr2, invdeg, ssrc, E);

    // ---- layer 1 ----
    agg_part_kernel<<<NBINS * NRANGE, 256, 0, stream>>>(xb, rowptr2, ssrc, part, N);
    mfma_linear_kernel<true><<<256, 256, 0, stream>>>(part, invdeg, xb, Wl1, b1, Wr1, hb, NG);

    // ---- layer 2 ----
    agg_part_kernel<<<NBINS * NRANGE, 256, 0, stream>>>(hb, rowptr2, ssrc, part, N);
    mfma_linear_kernel<false><<<256, 256, 0, stream>>>(part, invdeg, hb, Wl2, b2, Wr2, out, NG);
}